// Round 8
// baseline (2117.293 us; speedup 1.0000x reference)
//
#include <hip/hip_runtime.h>
#include <hip/hip_bf16.h>

// SparseLinear: out[b,s,o] = sum_i x[b,s,i]*W[o,i] + bias[o]
// M=8192, N=4096, K=4096. fp32 in/out; bf16 MFMA compute.
// Pass 1: convert x,W fp32->bf16 into d_ws.
// Pass 2: 256x256-tile GEMM, 8 waves, 16x16x32 MFMA.
// Round-8: BK 64->32, LDS 128->64 KiB => 2 blocks/CU (4 waves/SIMD) so a
// co-resident block covers barrier/wait stalls (m114 mechanism). Depth-1
// prefetch into the idle double-buffer half; VM(0)+BAR once per tile.
// LDS rows stay 128 B (two logical 32-elem rows packed) so the proven
// ((sr&7)<<4) XOR swizzle stays conflict-free.

typedef __attribute__((ext_vector_type(8))) short bf16x8;
typedef __attribute__((ext_vector_type(4))) float f32x4;
typedef unsigned short u16;

__device__ __forceinline__ u16 f2bf(float f) {
  unsigned int u = __float_as_uint(f);
  u += 0x7FFF + ((u >> 16) & 1);
  return (u16)(u >> 16);
}

__global__ __launch_bounds__(256) void convert_f32_bf16(
    const float* __restrict__ src, u16* __restrict__ dst, long long n) {
  long long stride = (long long)gridDim.x * blockDim.x * 4;
  for (long long e = ((long long)blockIdx.x * blockDim.x + threadIdx.x) * 4;
       e < n; e += stride) {
    float4 v = *reinterpret_cast<const float4*>(src + e);
    ushort4 o;
    o.x = f2bf(v.x); o.y = f2bf(v.y); o.z = f2bf(v.z); o.w = f2bf(v.w);
    *reinterpret_cast<ushort4*>(dst + e) = o;
  }
}

__device__ __forceinline__ void async16(const void* g, void* l) {
  __builtin_amdgcn_global_load_lds(
      (const __attribute__((address_space(1))) void*)g,
      (__attribute__((address_space(3))) void*)l, 16, 0, 0);
}

#define BAR()   asm volatile("s_barrier" ::: "memory")
#define LGKM0() asm volatile("s_waitcnt lgkmcnt(0)" ::: "memory")
#define VM0()   asm volatile("s_waitcnt vmcnt(0)" ::: "memory")
#define PRIO1() __builtin_amdgcn_s_setprio(1)
#define PRIO0() __builtin_amdgcn_s_setprio(0)

// ---------------- 256x256 BK=32 kernel ----------------
// LDS (bytes): A: buf c -> c*16384; B: 32768 + c*16384. Total 65536.
// Each buf: 128 storage rows x 128 B. Storage row sr packs logical rows
// (h=0: r=sr | h=1: r=sr+128) as [64B | 64B]; logical byte b_log =
// h*64 + k_elem*2; physical b_phys = b_log ^ ((sr&7)<<4) (involution).

__global__ __launch_bounds__(512, 4) void gemm256_bk32(
    const u16* __restrict__ A, const u16* __restrict__ B,
    const float* __restrict__ bias, float* __restrict__ C,
    int M, int N, int K) {
  extern __shared__ char smem[];
  char* ldsA = smem;
  char* ldsB = smem + 32768;

  const int tid  = threadIdx.x;
  const int lane = tid & 63;
  const int wave = tid >> 6;
  const int wm = wave >> 2;  // 0..1
  const int wn = wave & 3;   // 0..3

  // T1: XCD-aware block swizzle (grid divisible by 8)
  const int nwg = gridDim.x;
  const int cpx = nwg >> 3;
  const int bid = blockIdx.x;
  const int swz = (bid & 7) * cpx + (bid >> 3);
  const int nbn = N >> 8;
  const int m0 = (swz / nbn) << 8;
  const int n0 = (swz % nbn) << 8;

  // staging: dest d = j*8192 + tid*16 -> sr = j*64 + (tid>>3),
  // b_phys = (tid&7)*16, b_log = b_phys ^ (((tid>>3)&7)<<4),
  // logical row r = (b_log>>6)*128 + sr, col elem = (b_log&63)/2.
  const int bphys0 = (tid & 7) << 4;
  const int blog0  = bphys0 ^ (((tid >> 3) & 7) << 4);
  const int r0 = ((blog0 >> 6) << 7) + (tid >> 3);
  const int c0e = (blog0 & 63) >> 1;
  const u16* gA00 = A + (long long)(m0 + r0) * K + c0e;
  const u16* gB00 = B + (long long)(n0 + r0) * K + c0e;

  // stage tile S (k-elems S*32..S*32+31) into buf c
#define STAGE_A(c, S) do { \
  async16(gA00 + (S) * 32,                      ldsA + (c)*16384 + tid*16); \
  async16(gA00 + (long long)64 * K + (S) * 32,  ldsA + (c)*16384 + 8192 + tid*16); \
} while (0)
#define STAGE_B(c, S) do { \
  async16(gB00 + (S) * 32,                      ldsB + (c)*16384 + tid*16); \
  async16(gB00 + (long long)64 * K + (S) * 32,  ldsB + (c)*16384 + 8192 + tid*16); \
} while (0)

  // fragment read addresses (swizzled):
  // A m-frag mf: logical row = wm*128 + mf*16 + l15 -> h=wm, sr=mf*16+l15
  // B n-frag nf: logical col = wn*64 + nf*16 + l15 -> h=wn>>1, sr=(wn&1)*64+nf*16+l15
  // k-slot: lane>>4 -> b_log k-part = (lane>>4)*16
  const int l15 = lane & 15;
  const int g16 = (lane >> 4) << 4;
  const int xsw = (l15 & 7) << 4;
  const int apb = (wm * 64 + g16) ^ xsw;
  const int bpb = ((wn >> 1) * 64 + g16) ^ xsw;
  const int aro = l15 * 128 + apb;
  const int bro = ((wn & 1) * 64 + l15) * 128 + bpb;

#define LDA4(dst, c, lo) do { \
  _Pragma("unroll") for (int mf_ = 0; mf_ < 4; ++mf_) \
    dst[mf_] = *(const bf16x8*)(ldsA + (c)*16384 + ((lo) + mf_) * 2048 + aro); \
} while (0)
#define LDB4(dst, c) do { \
  _Pragma("unroll") for (int nf_ = 0; nf_ < 4; ++nf_) \
    dst[nf_] = *(const bf16x8*)(ldsB + (c)*16384 + nf_ * 2048 + bro); \
} while (0)

  f32x4 acc[8][4] = {};

#define MMQ(mb, af, bf) do { \
  _Pragma("unroll") for (int i_ = 0; i_ < 4; ++i_) \
  _Pragma("unroll") for (int j_ = 0; j_ < 4; ++j_) \
    acc[(mb)+i_][j_] = __builtin_amdgcn_mfma_f32_16x16x32_bf16( \
        af[i_], bf[j_], acc[(mb)+i_][j_], 0, 0, 0); \
} while (0)

// One BK=32 tile = 2 phases, 16 MFMA each. Stage T+1 into buf c^1 (idle
// during T: its last reader was T-1, drained before T-1's final barrier).
// VM0+BAR at tile end => T+1's 4 loads landed before GROUP(T+1) reads them.
#define GROUP(c, S, DO_STAGE) do { \
  bf16x8 a[4], a2[4], b[4]; \
  LDA4(a, c, 0); LDB4(b, c); \
  if (DO_STAGE) { STAGE_A((c) ^ 1, S); } \
  BAR(); LGKM0(); PRIO1(); MMQ(0, a, b); PRIO0(); BAR(); \
  LDA4(a2, c, 4); \
  if (DO_STAGE) { STAGE_B((c) ^ 1, S); } \
  BAR(); LGKM0(); PRIO1(); MMQ(4, a2, b); PRIO0(); \
  if (DO_STAGE) { VM0(); } \
  BAR(); \
} while (0)

  // Prologue: stage tile 0 into buf 0.
  STAGE_A(0, 0); STAGE_B(0, 0);
  VM0();
  __syncthreads();

  const int NT = K >> 5;  // 128
  for (int T = 0; T < NT; ++T) {
    GROUP(T & 1, T + 1, T < NT - 1);
  }

  // Epilogue: D layout col=lane&15, row=(lane>>4)*4+reg; fuse bias.
  const int row4 = (lane >> 4) << 2;
#pragma unroll
  for (int mf = 0; mf < 8; ++mf) {
#pragma unroll
    for (int nf = 0; nf < 4; ++nf) {
      const int gn = n0 + wn * 64 + nf * 16 + l15;
      const float bv = bias[gn];
      float* cp = C + (long long)(m0 + wm * 128 + mf * 16 + row4) * N + gn;
#pragma unroll
      for (int r = 0; r < 4; ++r) cp[(long long)r * N] = acc[mf][nf][r] + bv;
    }
  }
}

// ---------------- fallback: 128x128 kernel (static 16KB LDS) ----------------
__global__ __launch_bounds__(256) void gemm_bf16_bt(
    const u16* __restrict__ A, const u16* __restrict__ B,
    const float* __restrict__ bias, float* __restrict__ C,
    int M, int N, int K) {
  __shared__ u16 As[128 * 32];
  __shared__ u16 Bs[128 * 32];
  const int tid = threadIdx.x, lane = tid & 63, wave = tid >> 6;
  const int wr = wave >> 1, wc = wave & 1;
  const int nbn = N / 128;
  const int m0 = (blockIdx.x / nbn) * 128, n0 = (blockIdx.x % nbn) * 128;
  const int sr = tid >> 2, sc = (tid & 3) * 8;
  const u16* Ap0 = A + (long long)(m0 + sr) * K + sc;
  const u16* Ap1 = A + (long long)(m0 + 64 + sr) * K + sc;
  const u16* Bp0 = B + (long long)(n0 + sr) * K + sc;
  const u16* Bp1 = B + (long long)(n0 + 64 + sr) * K + sc;
  const int frow = lane & 15, fk = (lane >> 4) * 8;
  f32x4 acc[4][4] = {};
  for (int k0 = 0; k0 < K; k0 += 32) {
    async16(Ap0 + k0, As + tid * 8); async16(Ap1 + k0, As + 2048 + tid * 8);
    async16(Bp0 + k0, Bs + tid * 8); async16(Bp1 + k0, Bs + 2048 + tid * 8);
    __syncthreads();
    bf16x8 af[4], bfr[4];
#pragma unroll
    for (int i = 0; i < 4; ++i) {
      af[i]  = *reinterpret_cast<const bf16x8*>(As + (wr * 64 + i * 16 + frow) * 32 + fk);
      bfr[i] = *reinterpret_cast<const bf16x8*>(Bs + (wc * 64 + i * 16 + frow) * 32 + fk);
    }
#pragma unroll
    for (int i = 0; i < 4; ++i)
#pragma unroll
      for (int j = 0; j < 4; ++j)
        acc[i][j] = __builtin_amdgcn_mfma_f32_16x16x32_bf16(af[i], bfr[j], acc[i][j], 0, 0, 0);
    __syncthreads();
  }
  const int col0 = lane & 15, row4 = (lane >> 4) * 4;
#pragma unroll
  for (int i = 0; i < 4; ++i)
#pragma unroll
    for (int j = 0; j < 4; ++j) {
      const int n = n0 + wc * 64 + j * 16 + col0;
      const float bv = bias[n];
      const int mb = m0 + wr * 64 + i * 16 + row4;
#pragma unroll
      for (int r = 0; r < 4; ++r)
        C[(long long)(mb + r) * N + n] = acc[i][j][r] + bv;
    }
}

__global__ __launch_bounds__(256) void naive_gemm_f32(
    const float* __restrict__ x, const float* __restrict__ w,
    const float* __restrict__ bias, float* __restrict__ out,
    int M, int N, int K) {
  long long idx = (long long)blockIdx.x * 256 + threadIdx.x;
  if (idx >= (long long)M * N) return;
  int m = (int)(idx / N), n = (int)(idx % N);
  const float4* xr = reinterpret_cast<const float4*>(x + (long long)m * K);
  const float4* wr = reinterpret_cast<const float4*>(w + (long long)n * K);
  float s = 0.f;
  for (int k = 0; k < K / 4; ++k) {
    float4 a = xr[k], b = wr[k];
    s += a.x * b.x + a.y * b.y + a.z * b.z + a.w * b.w;
  }
  out[idx] = s + bias[n];
}

extern "C" void kernel_launch(void* const* d_in, const int* in_sizes, int n_in,
                              void* d_out, int out_size, void* d_ws,
                              size_t ws_size, hipStream_t stream) {
  const float* x    = (const float*)d_in[0];
  const float* w    = (const float*)d_in[1];
  const float* bias = (const float*)d_in[2];
  float* out = (float*)d_out;

  const int K = 4096, N = 4096;
  const long long xN = in_sizes[0];
  const long long wN = in_sizes[1];
  const int M = (int)(xN / K);

  const size_t need = (size_t)(xN + wN) * sizeof(u16);
  if (ws_size >= need) {
    u16* xb = (u16*)d_ws;
    u16* wb = xb + xN;
    convert_f32_bf16<<<2048, 256, 0, stream>>>(x, xb, xN);
    convert_f32_bf16<<<2048, 256, 0, stream>>>(w, wb, wN);
    hipError_t e = hipFuncSetAttribute(
        (const void*)gemm256_bk32,
        hipFuncAttributeMaxDynamicSharedMemorySize, 65536);
    if (e == hipSuccess && (M % 256) == 0 && (N % 256) == 0 && (K % 64) == 0) {
      const int grid = (M / 256) * (N / 256);  // 512
      gemm256_bk32<<<grid, 512, 65536, stream>>>(xb, wb, bias, out, M, N, K);
    } else {
      const int grid = (M / 128) * (N / 128);
      gemm_bf16_bt<<<grid, 256, 0, stream>>>(xb, wb, bias, out, M, N, K);
    }
  } else {
    const long long total = (long long)M * N;
    naive_gemm_f32<<<(unsigned)((total + 255) / 256), 256, 0, stream>>>(
        x, w, bias, out, M, N, K);
  }
}

// Round 9
// 426.756 us; speedup vs baseline: 4.9614x; 4.9614x over previous
//
#include <hip/hip_runtime.h>
#include <hip/hip_bf16.h>

// SparseLinear: out[b,s,o] = sum_i x[b,s,i]*W[o,i] + bias[o]
// M=8192, N=4096, K=4096. fp32 in/out; bf16 MFMA compute.
// Pass 1: convert x,W fp32->bf16 into d_ws.
// Pass 2: 256x256-tile, BK=64, 8-wave GEMM, m201 8-phase schedule:
//   2 K-tiles per iter (compile-time LDS buffer indices), 2 global_load_lds
//   per phase placed right after the barrier freeing that half-tile slot,
//   vmcnt(6) only at phases 4/8 (3 half-tiles in flight).
// Round-8 lesson: 256^2 8-wave needs ~200 regs/wave -> 2 waves/SIMD max;
// launch_bounds(512,4) spilled acc (6.5 GB scratch writes). Keep (512,2).

typedef __attribute__((ext_vector_type(8))) short bf16x8;
typedef __attribute__((ext_vector_type(4))) float f32x4;
typedef unsigned short u16;

__device__ __forceinline__ u16 f2bf(float f) {
  unsigned int u = __float_as_uint(f);
  u += 0x7FFF + ((u >> 16) & 1);
  return (u16)(u >> 16);
}

__global__ __launch_bounds__(256) void convert_f32_bf16(
    const float* __restrict__ src, u16* __restrict__ dst, long long n) {
  long long stride = (long long)gridDim.x * blockDim.x * 4;
  for (long long e = ((long long)blockIdx.x * blockDim.x + threadIdx.x) * 4;
       e < n; e += stride) {
    float4 v = *reinterpret_cast<const float4*>(src + e);
    ushort4 o;
    o.x = f2bf(v.x); o.y = f2bf(v.y); o.z = f2bf(v.z); o.w = f2bf(v.w);
    *reinterpret_cast<ushort4*>(dst + e) = o;
  }
}

__device__ __forceinline__ void async16(const void* g, void* l) {
  __builtin_amdgcn_global_load_lds(
      (const __attribute__((address_space(1))) void*)g,
      (__attribute__((address_space(3))) void*)l, 16, 0, 0);
}

#define BAR()   asm volatile("s_barrier" ::: "memory")
#define LGKM0() asm volatile("s_waitcnt lgkmcnt(0)" ::: "memory")
#define VM(n)   asm volatile("s_waitcnt vmcnt(" #n ")" ::: "memory")
#define PRIO1() __builtin_amdgcn_s_setprio(1)
#define PRIO0() __builtin_amdgcn_s_setprio(0)

// ---------------- 256x256 8-phase kernel ----------------
// LDS map (bytes): A: buf c -> c*32768, half h -> +h*16384 (128 rows x 128B).
//                  B: +65536, same. Total 131072.
// A half h holds m-frags {4h..4h+3}: storage row sr = wm*64 + mfl*16 + (r&15).
// B half h holds n-frags {2h,2h+1}:  storage row sr = wn*32 + nfl*16 + (r&15).
// Swizzle (involution): colbyte ^= ((sr&7)<<4).

__global__ __launch_bounds__(512, 2) void gemm256_8ph(
    const u16* __restrict__ A, const u16* __restrict__ B,
    const float* __restrict__ bias, float* __restrict__ C,
    int M, int N, int K) {
  extern __shared__ char smem[];
  char* ldsA = smem;
  char* ldsB = smem + 65536;

  const int tid  = threadIdx.x;
  const int lane = tid & 63;
  const int wave = tid >> 6;
  const int wm = wave >> 2;  // 0..1
  const int wn = wave & 3;   // 0..3

  // T1: XCD-aware block swizzle (grid divisible by 8)
  const int nwg = gridDim.x;
  const int cpx = nwg >> 3;
  const int bid = blockIdx.x;
  const int swz = (bid & 7) * cpx + (bid >> 3);
  const int nbn = N >> 8;
  const int m0 = (swz / nbn) << 8;
  const int n0 = (swz % nbn) << 8;

  // staging: linear LDS dest (tid*16 within half), pre-swizzled global source
  const int d0 = tid * 16;
  const int sr0 = d0 >> 7;              // 0..63 (issue j=0); j=1 adds 64 to sr
  const int cb0 = (d0 & 127) ^ ((sr0 & 7) << 4);
  const int rA0 = ((sr0 >> 6) << 7) + (((sr0 >> 4) & 3) << 4) + (sr0 & 15);
  const int rB0 = ((sr0 >> 5) << 6) + (((sr0 >> 4) & 1) << 4) + (sr0 & 15);
  const u16* gA00 = A + (long long)(m0 + rA0) * K + (cb0 >> 1);
  const u16* gB00 = B + (long long)(n0 + rB0) * K + (cb0 >> 1);

#define STAGE_A(c, h, S) do { \
  async16(gA00 + (long long)((h)*64)       * K + (S)*64, \
          ldsA + (c)*32768 + (h)*16384 + tid*16); \
  async16(gA00 + (long long)((h)*64 + 128) * K + (S)*64, \
          ldsA + (c)*32768 + (h)*16384 + 8192 + tid*16); \
} while (0)
#define STAGE_B(c, h, S) do { \
  async16(gB00 + (long long)((h)*32)       * K + (S)*64, \
          ldsB + (c)*32768 + (h)*16384 + tid*16); \
  async16(gB00 + (long long)((h)*32 + 128) * K + (S)*64, \
          ldsB + (c)*32768 + (h)*16384 + 8192 + tid*16); \
} while (0)

  // fragment read addresses (swizzled)
  const int l15 = lane & 15;
  const int csw0 = (((lane >> 4) * 16))      ^ ((lane & 7) << 4);  // kk=0
  const int csw1 = (64 + ((lane >> 4) * 16)) ^ ((lane & 7) << 4);  // kk=1
  const int arow = (wm * 64 + l15) * 128;
  const int brow = (wn * 32 + l15) * 128;

#define LDA(dst, c, h) do { \
  _Pragma("unroll") for (int mfl_ = 0; mfl_ < 4; ++mfl_) { \
    dst[mfl_][0] = *(const bf16x8*)(ldsA + (c)*32768 + (h)*16384 + arow + mfl_*2048 + csw0); \
    dst[mfl_][1] = *(const bf16x8*)(ldsA + (c)*32768 + (h)*16384 + arow + mfl_*2048 + csw1); \
  } } while (0)
#define LDB(dst, c, h) do { \
  _Pragma("unroll") for (int nfl_ = 0; nfl_ < 2; ++nfl_) { \
    dst[nfl_][0] = *(const bf16x8*)(ldsB + (c)*32768 + (h)*16384 + brow + nfl_*2048 + csw0); \
    dst[nfl_][1] = *(const bf16x8*)(ldsB + (c)*32768 + (h)*16384 + brow + nfl_*2048 + csw1); \
  } } while (0)

  f32x4 acc[8][4] = {};

#define MM(mb, nb, af, bf) do { \
  _Pragma("unroll") for (int i_ = 0; i_ < 4; ++i_) \
  _Pragma("unroll") for (int j_ = 0; j_ < 2; ++j_) \
  _Pragma("unroll") for (int kk_ = 0; kk_ < 2; ++kk_) \
    acc[(mb)+i_][(nb)+j_] = __builtin_amdgcn_mfma_f32_16x16x32_bf16( \
        af[i_][kk_], bf[j_][kk_], acc[(mb)+i_][(nb)+j_], 0, 0, 0); \
} while (0)

#define PHASE(MMA) do { \
  BAR(); LGKM0(); PRIO1(); MMA; PRIO0(); BAR(); \
} while (0)

  // Prologue: tile0 fully + tile1 A0,A1,B0 (B1(1) staged in iter-0 ph1).
  // 14 loads out; VM(6) completes tile0's 8.
  STAGE_A(0, 0, 0); STAGE_A(0, 1, 0); STAGE_B(0, 0, 0); STAGE_B(0, 1, 0);
  STAGE_A(1, 0, 1); STAGE_A(1, 1, 1); STAGE_B(1, 0, 1);
  VM(6);
  __syncthreads();

  bf16x8 a[4][2], a2[4][2], b[2][2], b2[2][2];

  // Iter i: compute tiles t=2i (buf0), u=2i+1 (buf1); stage p=2i+2 (buf0),
  // q=2i+3 (buf1). Slot-free proof per stage: the overwritten half's last
  // ds_read drained at LGKM0 before the preceding barrier.
  //   ph1: B1(u)->buf1 (free since prev ph7)   ph5: B1(p)->buf0 (free after ph3)
  //   ph2: A0(p)->buf0 (after ph1)             ph6: A0(q)->buf1 (after ph5)
  //   ph3: A1(p)->buf0 (after ph2)             ph7: A1(q)->buf1 (after ph6)
  //   ph4: B0(p)->buf0 (after ph1)             ph8: B0(q)->buf1 (after ph5)
  // VM(6)@ph4: 14 out -> oldest 8 (= tile u) landed; 6 (= p partial) fly.
  // VM(6)@ph8: 14 out -> oldest 8 (= tile p) landed; 6 (= q partial) fly.
  const int NT = K >> 6;       // 64 tiles
  const int NI = NT >> 1;      // 32 iters
  for (int i = 0; i < NI - 1; ++i) {
    const int S2 = 2 * i + 2, S3 = 2 * i + 3, U = 2 * i + 1;
    LDA(a, 0, 0); LDB(b, 0, 0); STAGE_B(1, 1, U);
    PHASE(MM(0, 0, a, b));
    LDA(a2, 0, 1); STAGE_A(0, 0, S2);
    PHASE(MM(4, 0, a2, b));
    LDB(b2, 0, 1); STAGE_A(0, 1, S2);
    PHASE(MM(4, 2, a2, b2));
    STAGE_B(0, 0, S2); VM(6);
    BAR(); PRIO1(); MM(0, 2, a, b2); PRIO0(); BAR();
    LDA(a, 1, 0); LDB(b, 1, 0); STAGE_B(0, 1, S2);
    PHASE(MM(0, 0, a, b));
    LDA(a2, 1, 1); STAGE_A(1, 0, S3);
    PHASE(MM(4, 0, a2, b));
    LDB(b2, 1, 1); STAGE_A(1, 1, S3);
    PHASE(MM(4, 2, a2, b2));
    STAGE_B(1, 0, S3); VM(6);
    BAR(); PRIO1(); MM(0, 2, a, b2); PRIO0(); BAR();
  }
  // Last iter (tiles NT-2, NT-1): ph1 stages B1(NT-1); VM(0)@ph4 drains the
  // remaining 8 (all tile NT-1); no further staging.
  LDA(a, 0, 0); LDB(b, 0, 0); STAGE_B(1, 1, NT - 1);
  PHASE(MM(0, 0, a, b));
  LDA(a2, 0, 1);
  PHASE(MM(4, 0, a2, b));
  LDB(b2, 0, 1);
  PHASE(MM(4, 2, a2, b2));
  VM(0);
  BAR(); PRIO1(); MM(0, 2, a, b2); PRIO0(); BAR();
  LDA(a, 1, 0); LDB(b, 1, 0);
  PHASE(MM(0, 0, a, b));
  LDA(a2, 1, 1);
  PHASE(MM(4, 0, a2, b));
  LDB(b2, 1, 1);
  PHASE(MM(4, 2, a2, b2));
  PRIO1(); MM(0, 2, a, b2); PRIO0();

  // Epilogue: D layout col=lane&15, row=(lane>>4)*4+reg; fuse bias.
  const int row4 = (lane >> 4) << 2;
#pragma unroll
  for (int mf = 0; mf < 8; ++mf) {
#pragma unroll
    for (int nf = 0; nf < 4; ++nf) {
      const int gn = n0 + wn * 64 + nf * 16 + l15;
      const float bv = bias[gn];
      float* cp = C + (long long)(m0 + wm * 128 + mf * 16 + row4) * N + gn;
#pragma unroll
      for (int r = 0; r < 4; ++r) cp[(long long)r * N] = acc[mf][nf][r] + bv;
    }
  }
}

// ---------------- fallback: 128x128 kernel (static 16KB LDS) ----------------
__global__ __launch_bounds__(256) void gemm_bf16_bt(
    const u16* __restrict__ A, const u16* __restrict__ B,
    const float* __restrict__ bias, float* __restrict__ C,
    int M, int N, int K) {
  __shared__ u16 As[128 * 32];
  __shared__ u16 Bs[128 * 32];
  const int tid = threadIdx.x, lane = tid & 63, wave = tid >> 6;
  const int wr = wave >> 1, wc = wave & 1;
  const int nbn = N / 128;
  const int m0 = (blockIdx.x / nbn) * 128, n0 = (blockIdx.x % nbn) * 128;
  const int sr = tid >> 2, sc = (tid & 3) * 8;
  const u16* Ap0 = A + (long long)(m0 + sr) * K + sc;
  const u16* Ap1 = A + (long long)(m0 + 64 + sr) * K + sc;
  const u16* Bp0 = B + (long long)(n0 + sr) * K + sc;
  const u16* Bp1 = B + (long long)(n0 + 64 + sr) * K + sc;
  const int frow = lane & 15, fk = (lane >> 4) * 8;
  f32x4 acc[4][4] = {};
  for (int k0 = 0; k0 < K; k0 += 32) {
    async16(Ap0 + k0, As + tid * 8); async16(Ap1 + k0, As + 2048 + tid * 8);
    async16(Bp0 + k0, Bs + tid * 8); async16(Bp1 + k0, Bs + 2048 + tid * 8);
    __syncthreads();
    bf16x8 af[4], bfr[4];
#pragma unroll
    for (int i = 0; i < 4; ++i) {
      af[i]  = *reinterpret_cast<const bf16x8*>(As + (wr * 64 + i * 16 + frow) * 32 + fk);
      bfr[i] = *reinterpret_cast<const bf16x8*>(Bs + (wc * 64 + i * 16 + frow) * 32 + fk);
    }
#pragma unroll
    for (int i = 0; i < 4; ++i)
#pragma unroll
      for (int j = 0; j < 4; ++j)
        acc[i][j] = __builtin_amdgcn_mfma_f32_16x16x32_bf16(af[i], bfr[j], acc[i][j], 0, 0, 0);
    __syncthreads();
  }
  const int col0 = lane & 15, row4 = (lane >> 4) * 4;
#pragma unroll
  for (int i = 0; i < 4; ++i)
#pragma unroll
    for (int j = 0; j < 4; ++j) {
      const int n = n0 + wc * 64 + j * 16 + col0;
      const float bv = bias[n];
      const int mb = m0 + wr * 64 + i * 16 + row4;
#pragma unroll
      for (int r = 0; r < 4; ++r)
        C[(long long)(mb + r) * N + n] = acc[i][j][r] + bv;
    }
}

__global__ __launch_bounds__(256) void naive_gemm_f32(
    const float* __restrict__ x, const float* __restrict__ w,
    const float* __restrict__ bias, float* __restrict__ out,
    int M, int N, int K) {
  long long idx = (long long)blockIdx.x * 256 + threadIdx.x;
  if (idx >= (long long)M * N) return;
  int m = (int)(idx / N), n = (int)(idx % N);
  const float4* xr = reinterpret_cast<const float4*>(x + (long long)m * K);
  const float4* wr = reinterpret_cast<const float4*>(w + (long long)n * K);
  float s = 0.f;
  for (int k = 0; k < K / 4; ++k) {
    float4 a = xr[k], b = wr[k];
    s += a.x * b.x + a.y * b.y + a.z * b.z + a.w * b.w;
  }
  out[idx] = s + bias[n];
}

extern "C" void kernel_launch(void* const* d_in, const int* in_sizes, int n_in,
                              void* d_out, int out_size, void* d_ws,
                              size_t ws_size, hipStream_t stream) {
  const float* x    = (const float*)d_in[0];
  const float* w    = (const float*)d_in[1];
  const float* bias = (const float*)d_in[2];
  float* out = (float*)d_out;

  const int K = 4096, N = 4096;
  const long long xN = in_sizes[0];
  const long long wN = in_sizes[1];
  const int M = (int)(xN / K);

  const size_t need = (size_t)(xN + wN) * sizeof(u16);
  if (ws_size >= need) {
    u16* xb = (u16*)d_ws;
    u16* wb = xb + xN;
    convert_f32_bf16<<<2048, 256, 0, stream>>>(x, xb, xN);
    convert_f32_bf16<<<2048, 256, 0, stream>>>(w, wb, wN);
    hipError_t e = hipFuncSetAttribute(
        (const void*)gemm256_8ph,
        hipFuncAttributeMaxDynamicSharedMemorySize, 131072);
    if (e == hipSuccess && (M % 256) == 0 && (N % 256) == 0 && (K % 128) == 0) {
      const int grid = (M / 256) * (N / 256);  // 512
      gemm256_8ph<<<grid, 512, 131072, stream>>>(xb, wb, bias, out, M, N, K);
    } else {
      const int grid = (M / 128) * (N / 128);
      gemm_bf16_bt<<<grid, 256, 0, stream>>>(xb, wb, bias, out, M, N, K);
    }
  } else {
    const long long total = (long long)M * N;
    naive_gemm_f32<<<(unsigned)((total + 255) / 256), 256, 0, stream>>>(
        x, w, bias, out, M, N, K);
  }
}

// Round 10
// 256.348 us; speedup vs baseline: 8.2594x; 1.6648x over previous
//
#include <hip/hip_runtime.h>
#include <hip/hip_bf16.h>

// SparseLinear: out[b,s,o] = sum_i x[b,s,i]*W[o,i] + bias[o]
// M=8192, N=4096, K=4096. fp32 in/out; bf16 MFMA compute.
// Pass 1: convert x,W fp32->bf16 into d_ws.
// Pass 2: 256x256-tile, BK=64, 8-wave GEMM.
// Round-10: SINGLE-barrier phases (4 bar/K-tile, was 8) with cross-phase
// pipelined ds_reads: phase = {LGKM0; MFMA; reads for next quadrant;
// 1 half-tile stage (2 gll); [VM]; BAR}. Reads issued in p are consumed in
// p+1 -> LDS-pipe work and drain overlap barrier-wait + other waves' MFMA.
// Slot proof: stage of X at phase p legal because X's reads were ISSUED
// before BAR(p-1) and DRAINED (owner LGKM0) before BAR(p-1).
// Ledger: VM(4) at P2 = 12 outstanding (T+1:8 + T+2:4) -> T+1 landed.

typedef __attribute__((ext_vector_type(8))) short bf16x8;
typedef __attribute__((ext_vector_type(4))) float f32x4;
typedef unsigned short u16;

__device__ __forceinline__ u16 f2bf(float f) {
  unsigned int u = __float_as_uint(f);
  u += 0x7FFF + ((u >> 16) & 1);
  return (u16)(u >> 16);
}

__global__ __launch_bounds__(256) void convert_f32_bf16(
    const float* __restrict__ src, u16* __restrict__ dst, long long n) {
  long long stride = (long long)gridDim.x * blockDim.x * 4;
  for (long long e = ((long long)blockIdx.x * blockDim.x + threadIdx.x) * 4;
       e < n; e += stride) {
    float4 v = *reinterpret_cast<const float4*>(src + e);
    ushort4 o;
    o.x = f2bf(v.x); o.y = f2bf(v.y); o.z = f2bf(v.z); o.w = f2bf(v.w);
    *reinterpret_cast<ushort4*>(dst + e) = o;
  }
}

__device__ __forceinline__ void async16(const void* g, void* l) {
  __builtin_amdgcn_global_load_lds(
      (const __attribute__((address_space(1))) void*)g,
      (__attribute__((address_space(3))) void*)l, 16, 0, 0);
}

#define BAR()   asm volatile("s_barrier" ::: "memory")
#define LGKM0() asm volatile("s_waitcnt lgkmcnt(0)" ::: "memory")
#define VM(n)   asm volatile("s_waitcnt vmcnt(" #n ")" ::: "memory")
#define PRIO1() __builtin_amdgcn_s_setprio(1)
#define PRIO0() __builtin_amdgcn_s_setprio(0)

// LDS map (bytes): A: buf c -> c*32768, half h -> +h*16384 (128 rows x 128B).
//                  B: +65536, same. Total 131072.
// A half h holds m-frags {4h..4h+3}: storage row sr = wm*64 + mfl*16 + (r&15).
// B half h holds n-frags {2h,2h+1}:  storage row sr = wn*32 + nfl*16 + (r&15).
// Swizzle (involution): colbyte ^= ((sr&7)<<4).

__global__ __launch_bounds__(512, 2) void gemm256_1bar(
    const u16* __restrict__ A, const u16* __restrict__ B,
    const float* __restrict__ bias, float* __restrict__ C,
    int M, int N, int K) {
  extern __shared__ char smem[];
  char* ldsA = smem;
  char* ldsB = smem + 65536;

  const int tid  = threadIdx.x;
  const int lane = tid & 63;
  const int wave = tid >> 6;
  const int wm = wave >> 2;  // 0..1
  const int wn = wave & 3;   // 0..3

  // T1: XCD-aware block swizzle (grid divisible by 8)
  const int nwg = gridDim.x;
  const int cpx = nwg >> 3;
  const int bid = blockIdx.x;
  const int swz = (bid & 7) * cpx + (bid >> 3);
  const int nbn = N >> 8;
  const int m0 = (swz / nbn) << 8;
  const int n0 = (swz % nbn) << 8;

  // staging: linear LDS dest (tid*16 within half), pre-swizzled global source
  const int d0 = tid * 16;
  const int sr0 = d0 >> 7;
  const int cb0 = (d0 & 127) ^ ((sr0 & 7) << 4);
  const int rA0 = ((sr0 >> 6) << 7) + (((sr0 >> 4) & 3) << 4) + (sr0 & 15);
  const int rB0 = ((sr0 >> 5) << 6) + (((sr0 >> 4) & 1) << 4) + (sr0 & 15);
  const u16* gA00 = A + (long long)(m0 + rA0) * K + (cb0 >> 1);
  const u16* gB00 = B + (long long)(n0 + rB0) * K + (cb0 >> 1);

#define STAGE_A(c, h, S) do { \
  async16(gA00 + (long long)((h)*64)       * K + (S)*64, \
          ldsA + (c)*32768 + (h)*16384 + tid*16); \
  async16(gA00 + (long long)((h)*64 + 128) * K + (S)*64, \
          ldsA + (c)*32768 + (h)*16384 + 8192 + tid*16); \
} while (0)
#define STAGE_B(c, h, S) do { \
  async16(gB00 + (long long)((h)*32)       * K + (S)*64, \
          ldsB + (c)*32768 + (h)*16384 + tid*16); \
  async16(gB00 + (long long)((h)*32 + 128) * K + (S)*64, \
          ldsB + (c)*32768 + (h)*16384 + 8192 + tid*16); \
} while (0)

  // fragment read addresses (swizzled)
  const int l15 = lane & 15;
  const int csw0 = (((lane >> 4) * 16))      ^ ((lane & 7) << 4);
  const int csw1 = (64 + ((lane >> 4) * 16)) ^ ((lane & 7) << 4);
  const int arow = (wm * 64 + l15) * 128;
  const int brow = (wn * 32 + l15) * 128;

#define LDA(dst, c, h) do { \
  _Pragma("unroll") for (int mfl_ = 0; mfl_ < 4; ++mfl_) { \
    dst[mfl_][0] = *(const bf16x8*)(ldsA + (c)*32768 + (h)*16384 + arow + mfl_*2048 + csw0); \
    dst[mfl_][1] = *(const bf16x8*)(ldsA + (c)*32768 + (h)*16384 + arow + mfl_*2048 + csw1); \
  } } while (0)
#define LDB(dst, c, h) do { \
  _Pragma("unroll") for (int nfl_ = 0; nfl_ < 2; ++nfl_) { \
    dst[nfl_][0] = *(const bf16x8*)(ldsB + (c)*32768 + (h)*16384 + brow + nfl_*2048 + csw0); \
    dst[nfl_][1] = *(const bf16x8*)(ldsB + (c)*32768 + (h)*16384 + brow + nfl_*2048 + csw1); \
  } } while (0)

  f32x4 acc[8][4] = {};

#define MM(mb, nb, af, bf) do { \
  _Pragma("unroll") for (int i_ = 0; i_ < 4; ++i_) \
  _Pragma("unroll") for (int j_ = 0; j_ < 2; ++j_) \
  _Pragma("unroll") for (int kk_ = 0; kk_ < 2; ++kk_) \
    acc[(mb)+i_][(nb)+j_] = __builtin_amdgcn_mfma_f32_16x16x32_bf16( \
        af[i_][kk_], bf[j_][kk_], acc[(mb)+i_][(nb)+j_], 0, 0, 0); \
} while (0)

  // Prologue: stage tiles 0 (buf0) and 1 (buf1); VM(8) -> tile0 landed
  // (per-wave; barrier makes it block-wide). Then pre-read a(0), b(0).
  STAGE_A(0, 0, 0); STAGE_A(0, 1, 0); STAGE_B(0, 0, 0); STAGE_B(0, 1, 0);
  STAGE_A(1, 0, 1); STAGE_A(1, 1, 1); STAGE_B(1, 0, 1); STAGE_B(1, 1, 1);
  VM(8);
  __syncthreads();

  bf16x8 a[4][2], a2[4][2], b[2][2], b2[2][2];
  LDA(a, 0, 0); LDB(b, 0, 0);

  // Quadrant order: P1 (a,b) -> P2 (a2,b) -> P3 (a,b2) -> P4 (a2,b2).
  // Reads: a2@P1, b2@P2, a(T+1)@P3, b(T+1)@P4 (after their last MM use).
  // Stages (tile T+2 into buf c=T&1): A0@P1(T>0; @P2 for T=0), B0@P2,
  // A1@P3, B1@P4 — each slot's readers issued+drained before BAR(p-1).
  const int NT = K >> 6;  // 64
  for (int T = 0; T < NT; ++T) {
    const int c = T & 1;
    const int S = T + 2;
    const bool st = S < NT;
    const bool nx = T + 1 < NT;
    // P1
    LGKM0(); PRIO1(); MM(0, 0, a, b); PRIO0();
    LDA(a2, c, 1);
    if (st && T) STAGE_A(c, 0, S);
    BAR();
    // P2
    LGKM0(); PRIO1(); MM(4, 0, a2, b); PRIO0();
    LDB(b2, c, 1);
    if (st) { if (!T) STAGE_A(c, 0, S); STAGE_B(c, 0, S); }
    if (st) { VM(4); } else { VM(0); }
    BAR();
    // P3
    LGKM0(); PRIO1(); MM(0, 2, a, b2); PRIO0();
    if (nx) LDA(a, c ^ 1, 0);
    if (st) STAGE_A(c, 1, S);
    BAR();
    // P4
    LGKM0(); PRIO1(); MM(4, 2, a2, b2); PRIO0();
    if (nx) LDB(b, c ^ 1, 0);
    if (st) STAGE_B(c, 1, S);
    BAR();
  }

  // Epilogue: D layout col=lane&15, row=(lane>>4)*4+reg; fuse bias.
  const int row4 = (lane >> 4) << 2;
#pragma unroll
  for (int mf = 0; mf < 8; ++mf) {
#pragma unroll
    for (int nf = 0; nf < 4; ++nf) {
      const int gn = n0 + wn * 64 + nf * 16 + l15;
      const float bv = bias[gn];
      float* cp = C + (long long)(m0 + wm * 128 + mf * 16 + row4) * N + gn;
#pragma unroll
      for (int r = 0; r < 4; ++r) cp[(long long)r * N] = acc[mf][nf][r] + bv;
    }
  }
}

// ---------------- fallback: 128x128 kernel (static 16KB LDS) ----------------
__global__ __launch_bounds__(256) void gemm_bf16_bt(
    const u16* __restrict__ A, const u16* __restrict__ B,
    const float* __restrict__ bias, float* __restrict__ C,
    int M, int N, int K) {
  __shared__ u16 As[128 * 32];
  __shared__ u16 Bs[128 * 32];
  const int tid = threadIdx.x, lane = tid & 63, wave = tid >> 6;
  const int wr = wave >> 1, wc = wave & 1;
  const int nbn = N / 128;
  const int m0 = (blockIdx.x / nbn) * 128, n0 = (blockIdx.x % nbn) * 128;
  const int sr = tid >> 2, sc = (tid & 3) * 8;
  const u16* Ap0 = A + (long long)(m0 + sr) * K + sc;
  const u16* Ap1 = A + (long long)(m0 + 64 + sr) * K + sc;
  const u16* Bp0 = B + (long long)(n0 + sr) * K + sc;
  const u16* Bp1 = B + (long long)(n0 + 64 + sr) * K + sc;
  const int frow = lane & 15, fk = (lane >> 4) * 8;
  f32x4 acc[4][4] = {};
  for (int k0 = 0; k0 < K; k0 += 32) {
    async16(Ap0 + k0, As + tid * 8); async16(Ap1 + k0, As + 2048 + tid * 8);
    async16(Bp0 + k0, Bs + tid * 8); async16(Bp1 + k0, Bs + 2048 + tid * 8);
    __syncthreads();
    bf16x8 af[4], bfr[4];
#pragma unroll
    for (int i = 0; i < 4; ++i) {
      af[i]  = *reinterpret_cast<const bf16x8*>(As + (wr * 64 + i * 16 + frow) * 32 + fk);
      bfr[i] = *reinterpret_cast<const bf16x8*>(Bs + (wc * 64 + i * 16 + frow) * 32 + fk);
    }
#pragma unroll
    for (int i = 0; i < 4; ++i)
#pragma unroll
      for (int j = 0; j < 4; ++j)
        acc[i][j] = __builtin_amdgcn_mfma_f32_16x16x32_bf16(af[i], bfr[j], acc[i][j], 0, 0, 0);
    __syncthreads();
  }
  const int col0 = lane & 15, row4 = (lane >> 4) * 4;
#pragma unroll
  for (int i = 0; i < 4; ++i)
#pragma unroll
    for (int j = 0; j < 4; ++j) {
      const int n = n0 + wc * 64 + j * 16 + col0;
      const float bv = bias[n];
      const int mb = m0 + wr * 64 + i * 16 + row4;
#pragma unroll
      for (int r = 0; r < 4; ++r)
        C[(long long)(mb + r) * N + n] = acc[i][j][r] + bv;
    }
}

__global__ __launch_bounds__(256) void naive_gemm_f32(
    const float* __restrict__ x, const float* __restrict__ w,
    const float* __restrict__ bias, float* __restrict__ out,
    int M, int N, int K) {
  long long idx = (long long)blockIdx.x * 256 + threadIdx.x;
  if (idx >= (long long)M * N) return;
  int m = (int)(idx / N), n = (int)(idx % N);
  const float4* xr = reinterpret_cast<const float4*>(x + (long long)m * K);
  const float4* wr = reinterpret_cast<const float4*>(w + (long long)n * K);
  float s = 0.f;
  for (int k = 0; k < K / 4; ++k) {
    float4 a = xr[k], b = wr[k];
    s += a.x * b.x + a.y * b.y + a.z * b.z + a.w * b.w;
  }
  out[idx] = s + bias[n];
}

extern "C" void kernel_launch(void* const* d_in, const int* in_sizes, int n_in,
                              void* d_out, int out_size, void* d_ws,
                              size_t ws_size, hipStream_t stream) {
  const float* x    = (const float*)d_in[0];
  const float* w    = (const float*)d_in[1];
  const float* bias = (const float*)d_in[2];
  float* out = (float*)d_out;

  const int K = 4096, N = 4096;
  const long long xN = in_sizes[0];
  const long long wN = in_sizes[1];
  const int M = (int)(xN / K);

  const size_t need = (size_t)(xN + wN) * sizeof(u16);
  if (ws_size >= need) {
    u16* xb = (u16*)d_ws;
    u16* wb = xb + xN;
    convert_f32_bf16<<<2048, 256, 0, stream>>>(x, xb, xN);
    convert_f32_bf16<<<2048, 256, 0, stream>>>(w, wb, wN);
    hipError_t e = hipFuncSetAttribute(
        (const void*)gemm256_1bar,
        hipFuncAttributeMaxDynamicSharedMemorySize, 131072);
    if (e == hipSuccess && (M % 256) == 0 && (N % 256) == 0 && (K % 128) == 0) {
      const int grid = (M / 256) * (N / 256);  // 512
      gemm256_1bar<<<grid, 512, 131072, stream>>>(xb, wb, bias, out, M, N, K);
    } else {
      const int grid = (M / 128) * (N / 128);
      gemm_bf16_bt<<<grid, 256, 0, stream>>>(xb, wb, bias, out, M, N, K);
    }
  } else {
    const long long total = (long long)M * N;
    naive_gemm_f32<<<(unsigned)((total + 255) / 256), 256, 0, stream>>>(
        x, w, bias, out, M, N, K);
  }
}